// Round 1
// baseline (323.808 us; speedup 1.0000x reference)
//
#include <hip/hip_runtime.h>
#include <math.h>

#define BB 64
#define CC 1024
#define QQ 256
#define DD 128
#define NEGV (-1.0e30f)

typedef short bf8 __attribute__((ext_vector_type(8)));
typedef short bf4 __attribute__((ext_vector_type(4)));
typedef float f4v __attribute__((ext_vector_type(4)));

__device__ __forceinline__ short f2bf(float f) {
    unsigned u = __builtin_bit_cast(unsigned, f);
    u += 0x7FFFu + ((u >> 16) & 1u);            // RNE
    return (short)(u >> 16);
}
__device__ __forceinline__ float bf2f(short s) {
    unsigned u = ((unsigned)(unsigned short)s) << 16;
    return __builtin_bit_cast(float, u);
}

// ---------------- k0: fused convert + transpose + masked s-vector ----------------
// One pass over src fp32 [B][R][128]:
//   rm[b][r][d]  = bf16(src * (MULW2 ? W2[d] : 1))      (row-major)
//   tr[b][d][r]  = bf16(src)                            (transposed)
//   sm[b][r]     = src[r] . W  + NEG*(1-mask[r])        (mask folded here)
template <int MULW2>
__global__ __launch_bounds__(256, 2) void k0_fused(const float* __restrict__ src,
                                                   const float* __restrict__ W,
                                                   const float* __restrict__ W2,
                                                   const float* __restrict__ mask,
                                                   float* __restrict__ sm,
                                                   short* __restrict__ rm,
                                                   short* __restrict__ tr, int R) {
    __shared__ float tile[64][132];
    int tiles = R >> 6;
    int b = blockIdx.x / tiles, tl = blockIdx.x - b * tiles;
    int r0 = tl * 64;
    int t = threadIdx.x;
    int c4 = t & 31, rr = t >> 5;
    float4 wv = ((const float4*)W)[c4];
    float4 w2v{};
    if constexpr (MULW2) w2v = ((const float4*)W2)[c4];
    const float* sb = src + ((size_t)b * R + r0) * DD;
    #pragma unroll
    for (int p = 0; p < 8; ++p) {
        int row = rr + p * 8;
        float4 g = *(const float4*)&sb[(size_t)row * DD + c4 * 4];
        bf4 o;
        if constexpr (MULW2) {
            o[0] = f2bf(g.x * w2v.x); o[1] = f2bf(g.y * w2v.y);
            o[2] = f2bf(g.z * w2v.z); o[3] = f2bf(g.w * w2v.w);
        } else {
            o[0] = f2bf(g.x); o[1] = f2bf(g.y);
            o[2] = f2bf(g.z); o[3] = f2bf(g.w);
        }
        *(bf4*)&rm[((size_t)(b * R + r0 + row)) * DD + c4 * 4] = o;
        float part = g.x * wv.x + g.y * wv.y + g.z * wv.z + g.w * wv.w;
        #pragma unroll
        for (int off = 1; off < 32; off <<= 1) part += __shfl_xor(part, off, 64);
        if ((t & 31) == 0)
            sm[(size_t)b * R + r0 + row] =
                part + NEGV * (1.0f - mask[(size_t)b * R + r0 + row]);
        *(float4*)&tile[row][c4 * 4] = g;
    }
    __syncthreads();
    int d = t >> 1, rh = (t & 1) * 32;
    #pragma unroll
    for (int k = 0; k < 8; ++k) {
        bf4 o;
        #pragma unroll
        for (int i = 0; i < 4; ++i) o[i] = f2bf(tile[rh + k * 4 + i][d]);
        *(bf4*)&tr[((size_t)(b * DD + d)) * R + r0 + rh + k * 4] = o;
    }
}

#define SCP 1032   // k1 score row stride (bf16)
#define S2P 264    // k2 score row stride (bf16)

// ---------------- k1: col softmax over c, AT[b][d][q] ----------------
// Direct-from-global MFMA fragments (no staging LDS, 2 barriers total).
// XCD swizzle: bid = x + 8*(qt + 16*bh), b = bh*8+x  -> whole batch on one XCD.
__global__ __launch_bounds__(256, 4) void k1_colsm(
        const short* __restrict__ xc_bf, const short* __restrict__ xcT_bf,
        const short* __restrict__ xqw_bf, const float* __restrict__ s0m,
        short* __restrict__ AT) {
    __shared__ __align__(16) short sc[16][SCP];   // 33.0 KB scores/weights [q][c]
    __shared__ float invl[16];

    int bid = blockIdx.x;
    int qt = (bid >> 3) & 15;
    int b = ((bid >> 7) << 3) | (bid & 7);
    int q0 = qt * 16;
    int t = threadIdx.x, w = t >> 6, l = t & 63;
    int quad = l >> 4, l16 = l & 15;

    // block-constant B-op: 16 xqw rows, fragment-resident
    bf8 bq[4];
    {
        const short* qp = &xqw_bf[(size_t)(b * QQ + q0 + l16) * DD + quad * 8];
        #pragma unroll
        for (int ks = 0; ks < 4; ++ks) bq[ks] = *(const bf8*)&qp[ks * 32];
    }

    // ---- phase A: S[c][q] for all 1024 c (M=c, N=q, K=d), barrier-free ----
    const short* abase = &xc_bf[(size_t)(b * CC + w * 16 + l16) * DD + quad * 8];
    const float* s0base = &s0m[b * CC + w * 16 + quad * 4];
    for (int ct = 0; ct < 16; ++ct) {
        const short* ar = abase + (size_t)ct * 64 * DD;
        f4v acc = {0.f, 0.f, 0.f, 0.f};
        #pragma unroll
        for (int ks = 0; ks < 4; ++ks) {
            bf8 a = *(const bf8*)&ar[ks * 32];
            acc = __builtin_amdgcn_mfma_f32_16x16x32_bf16(a, bq[ks], acc, 0, 0, 0);
        }
        f4v s0v = *(const f4v*)&s0base[ct * 64];
        bf4 ov;
        #pragma unroll
        for (int r = 0; r < 4; ++r) ov[r] = f2bf(acc[r] + s0v[r]);
        *(bf4*)&sc[l16][ct * 64 + w * 16 + quad * 4] = ov;  // col=q=l16, row=c
    }
    __syncthreads();

    // ---- phase B: softmax over c per q ----
    {
        int q = t >> 4, k = t & 15;
        float m = -3.0e38f;
        #pragma unroll 8
        for (int i = 0; i < 64; ++i) m = fmaxf(m, bf2f(sc[q][k + 16 * i]));
        #pragma unroll
        for (int off = 1; off < 16; off <<= 1) m = fmaxf(m, __shfl_xor(m, off, 64));
        float sum = 0.f;
        #pragma unroll 8
        for (int i = 0; i < 64; ++i) {
            int idx = k + 16 * i;
            float e = __expf(bf2f(sc[q][idx]) - m);
            sc[q][idx] = f2bf(e);
            sum += e;
        }
        #pragma unroll
        for (int off = 1; off < 16; off <<= 1) sum += __shfl_xor(sum, off, 64);
        if (k == 0) invl[q] = 1.0f / sum;
    }
    __syncthreads();

    // ---- phase C: AT (M=q, N=d, K=c); A = sc LDS, B = xcT direct global ----
    f4v acc0 = {0.f, 0.f, 0.f, 0.f}, acc1 = {0.f, 0.f, 0.f, 0.f};
    const short* b0base = &xcT_bf[(size_t)(b * DD + w * 32 + l16) * CC + quad * 8];
    const short* b1base = b0base + (size_t)16 * CC;
    for (int ct = 0; ct < 16; ++ct) {
        #pragma unroll
        for (int ks = 0; ks < 2; ++ks) {
            bf8 a = *(const bf8*)&sc[l16][ct * 64 + ks * 32 + quad * 8];
            bf8 b0 = *(const bf8*)&b0base[ct * 64 + ks * 32];
            acc0 = __builtin_amdgcn_mfma_f32_16x16x32_bf16(a, b0, acc0, 0, 0, 0);
            bf8 b1 = *(const bf8*)&b1base[ct * 64 + ks * 32];
            acc1 = __builtin_amdgcn_mfma_f32_16x16x32_bf16(a, b1, acc1, 0, 0, 0);
        }
    }
    {
        bf4 o0, o1;
        #pragma unroll
        for (int r = 0; r < 4; ++r) {
            float il = invl[quad * 4 + r];
            o0[r] = f2bf(acc0[r] * il);
            o1[r] = f2bf(acc1[r] * il);
        }
        int d0 = w * 32 + l16;
        *(bf4*)&AT[(size_t)(b * DD + d0) * QQ + q0 + quad * 4] = o0;
        *(bf4*)&AT[(size_t)(b * DD + d0 + 16) * QQ + q0 + quad * 4] = o1;
    }
}

// ---------------- k2: row softmax over q, c2q / q2c, fused concat ----------------
// Direct-from-global fragments, 2 barriers. bid = x + 8*(cb + 32*bh), b = bh*8+x.
__global__ __launch_bounds__(256, 4) void k2_rowsm(
        const float* __restrict__ xc, const short* __restrict__ xc_bf,
        const short* __restrict__ xqw_bf, const short* __restrict__ xqT_bf,
        const short* __restrict__ AT, const float* __restrict__ s1m,
        float* __restrict__ out) {
    __shared__ __align__(16) short sc2[32][S2P];  // 16.9 KB scores/weights [c][q]
    __shared__ float invl2[32];

    int bid = blockIdx.x;
    int cb = (bid >> 3) & 31;
    int b = ((bid >> 8) << 3) | (bid & 7);
    int c0g = cb * 32;
    int t = threadIdx.x, w = t >> 6, l = t & 63;
    int quad = l >> 4, l16 = l & 15;

    // block-constant B-op: 32 xc rows, fragment-resident
    bf8 bc0[4], bc1[4];
    {
        const short* p0 = &xc_bf[(size_t)(b * CC + c0g + l16) * DD + quad * 8];
        const short* p1 = p0 + 16 * DD;
        #pragma unroll
        for (int ks = 0; ks < 4; ++ks) {
            bc0[ks] = *(const bf8*)&p0[ks * 32];
            bc1[ks] = *(const bf8*)&p1[ks * 32];
        }
    }

    // ---- phase 1: S^T (M=q, N=c, K=d), barrier-free ----
    const short* abase = &xqw_bf[(size_t)(b * QQ + w * 16 + l16) * DD + quad * 8];
    const float* s1base = &s1m[b * QQ + w * 16 + quad * 4];
    #pragma unroll
    for (int qt = 0; qt < 4; ++qt) {
        const short* ar = abase + (size_t)qt * 64 * DD;
        f4v acc0 = {0.f, 0.f, 0.f, 0.f}, acc1 = {0.f, 0.f, 0.f, 0.f};
        #pragma unroll
        for (int ks = 0; ks < 4; ++ks) {
            bf8 a = *(const bf8*)&ar[ks * 32];
            acc0 = __builtin_amdgcn_mfma_f32_16x16x32_bf16(a, bc0[ks], acc0, 0, 0, 0);
            acc1 = __builtin_amdgcn_mfma_f32_16x16x32_bf16(a, bc1[ks], acc1, 0, 0, 0);
        }
        int qbase = qt * 64 + w * 16 + quad * 4;
        f4v sv = *(const f4v*)&s1base[qt * 64];
        bf4 o0, o1;
        #pragma unroll
        for (int r = 0; r < 4; ++r) {
            o0[r] = f2bf(acc0[r] + sv[r]);
            o1[r] = f2bf(acc1[r] + sv[r]);
        }
        *(bf4*)&sc2[l16][qbase] = o0;        // col=c=l16, rows=q
        *(bf4*)&sc2[16 + l16][qbase] = o1;
    }
    __syncthreads();

    // ---- phase 2: softmax over q per c ----
    {
        int c = t >> 3, k = t & 7;
        float m = -3.0e38f;
        #pragma unroll 8
        for (int i = 0; i < 32; ++i) m = fmaxf(m, bf2f(sc2[c][k + 8 * i]));
        #pragma unroll
        for (int off = 1; off < 8; off <<= 1) m = fmaxf(m, __shfl_xor(m, off, 64));
        float sum = 0.f;
        #pragma unroll 8
        for (int i = 0; i < 32; ++i) {
            int idx = k + 8 * i;
            float e = __expf(bf2f(sc2[c][idx]) - m);
            sc2[c][idx] = f2bf(e);
            sum += e;
        }
        #pragma unroll
        for (int off = 1; off < 8; off <<= 1) sum += __shfl_xor(sum, off, 64);
        if (k == 0) invl2[c] = 1.0f / sum;
    }
    __syncthreads();

    // ---- phase 3: c2q = W@xq, q2c = W@A (M=c, N=d, K=q), fused loops ----
    int cb16 = (w & 1) * 16, dh = (w >> 1) * 64;
    f4v ac[4], aq[4];
    f4v zz = {0.f, 0.f, 0.f, 0.f};
    #pragma unroll
    for (int n = 0; n < 4; ++n) { ac[n] = zz; aq[n] = zz; }
    const short* bqt = &xqT_bf[(size_t)(b * DD + dh + l16) * QQ + quad * 8];
    const short* bat = &AT[(size_t)(b * DD + dh + l16) * QQ + quad * 8];
    #pragma unroll
    for (int qt = 0; qt < 4; ++qt) {
        #pragma unroll
        for (int ks = 0; ks < 2; ++ks) {
            bf8 a = *(const bf8*)&sc2[cb16 + l16][qt * 64 + ks * 32 + quad * 8];
            #pragma unroll
            for (int n = 0; n < 4; ++n) {
                bf8 bb = *(const bf8*)&bqt[(size_t)(n * 16) * QQ + qt * 64 + ks * 32];
                ac[n] = __builtin_amdgcn_mfma_f32_16x16x32_bf16(a, bb, ac[n], 0, 0, 0);
            }
            #pragma unroll
            for (int n = 0; n < 4; ++n) {
                bf8 bb = *(const bf8*)&bat[(size_t)(n * 16) * QQ + qt * 64 + ks * 32];
                aq[n] = __builtin_amdgcn_mfma_f32_16x16x32_bf16(a, bb, aq[n], 0, 0, 0);
            }
        }
    }

    // ---- epilogue: concat([xc, c2q, xc*c2q, xc*q2c]) ----
    #pragma unroll
    for (int r = 0; r < 4; ++r) {
        int c = c0g + cb16 + quad * 4 + r;
        float il = invl2[cb16 + quad * 4 + r];
        const float* xrow = xc + (size_t)(b * CC + c) * DD;
        float* orow = out + (size_t)(b * CC + c) * (4 * DD);
        #pragma unroll
        for (int n = 0; n < 4; ++n) {
            int d = dh + n * 16 + l16;
            float xv = xrow[d];
            float c2v = ac[n][r] * il;
            float q2v = aq[n][r] * il;
            orow[d] = xv;
            orow[DD + d] = c2v;
            orow[2 * DD + d] = xv * c2v;
            orow[3 * DD + d] = xv * q2v;
        }
    }
}

extern "C" void kernel_launch(void* const* d_in, const int* in_sizes, int n_in,
                              void* d_out, int out_size, void* d_ws, size_t ws_size,
                              hipStream_t stream) {
    const float* x_cont = (const float*)d_in[0];
    const float* x_ques = (const float*)d_in[1];
    const float* c_mask = (const float*)d_in[2];
    const float* q_mask = (const float*)d_in[3];
    const float* W0     = (const float*)d_in[4];
    const float* W1     = (const float*)d_in[5];
    const float* W2     = (const float*)d_in[6];
    // bias cancels in both softmaxes.
    float* out = (float*)d_out;

    char* ws = (char*)d_ws;
    float* s0m    = (float*)ws;  ws += (size_t)BB * CC * 4;
    float* s1m    = (float*)ws;  ws += (size_t)BB * QQ * 4;
    short* xc_bf  = (short*)ws;  ws += (size_t)BB * CC * DD * 2;
    short* xqw_bf = (short*)ws;  ws += (size_t)BB * QQ * DD * 2;
    short* xcT_bf = (short*)ws;  ws += (size_t)BB * CC * DD * 2;
    short* xqT_bf = (short*)ws;  ws += (size_t)BB * QQ * DD * 2;
    short* AT     = (short*)ws;  // B*D*Q

    k0_fused<0><<<BB * (CC / 64), 256, 0, stream>>>(x_cont, W0, nullptr, c_mask,
                                                    s0m, xc_bf, xcT_bf, CC);
    k0_fused<1><<<BB * (QQ / 64), 256, 0, stream>>>(x_ques, W1, W2, q_mask,
                                                    s1m, xqw_bf, xqT_bf, QQ);
    k1_colsm<<<BB * 16, 256, 0, stream>>>(xc_bf, xcT_bf, xqw_bf, s0m, AT);
    k2_rowsm<<<BB * 32, 256, 0, stream>>>(x_cont, xc_bf, xqw_bf, xqT_bf, AT, s1m, out);
}

// Round 2
// 277.210 us; speedup vs baseline: 1.1681x; 1.1681x over previous
//
#include <hip/hip_runtime.h>
#include <math.h>

#define BB 64
#define CC 1024
#define QQ 256
#define DD 128
#define NEGV (-1.0e30f)

typedef short bf8 __attribute__((ext_vector_type(8)));
typedef short bf4 __attribute__((ext_vector_type(4)));
typedef float f4v __attribute__((ext_vector_type(4)));

__device__ __forceinline__ short f2bf(float f) {
    unsigned u = __builtin_bit_cast(unsigned, f);
    u += 0x7FFFu + ((u >> 16) & 1u);            // RNE
    return (short)(u >> 16);
}
__device__ __forceinline__ float bf2f(short s) {
    unsigned u = ((unsigned)(unsigned short)s) << 16;
    return __builtin_bit_cast(float, u);
}

// ---------------- k0: fused convert + transpose + masked s-vector ----------------
template <int MULW2>
__global__ __launch_bounds__(256, 2) void k0_fused(const float* __restrict__ src,
                                                   const float* __restrict__ W,
                                                   const float* __restrict__ W2,
                                                   const float* __restrict__ mask,
                                                   float* __restrict__ sm,
                                                   short* __restrict__ rm,
                                                   short* __restrict__ tr, int R) {
    __shared__ float tile[64][132];
    int tiles = R >> 6;
    int b = blockIdx.x / tiles, tl = blockIdx.x - b * tiles;
    int r0 = tl * 64;
    int t = threadIdx.x;
    int c4 = t & 31, rr = t >> 5;
    float4 wv = ((const float4*)W)[c4];
    float4 w2v{};
    if constexpr (MULW2) w2v = ((const float4*)W2)[c4];
    const float* sb = src + ((size_t)b * R + r0) * DD;
    #pragma unroll
    for (int p = 0; p < 8; ++p) {
        int row = rr + p * 8;
        float4 g = *(const float4*)&sb[(size_t)row * DD + c4 * 4];
        bf4 o;
        if constexpr (MULW2) {
            o[0] = f2bf(g.x * w2v.x); o[1] = f2bf(g.y * w2v.y);
            o[2] = f2bf(g.z * w2v.z); o[3] = f2bf(g.w * w2v.w);
        } else {
            o[0] = f2bf(g.x); o[1] = f2bf(g.y);
            o[2] = f2bf(g.z); o[3] = f2bf(g.w);
        }
        *(bf4*)&rm[((size_t)(b * R + r0 + row)) * DD + c4 * 4] = o;
        float part = g.x * wv.x + g.y * wv.y + g.z * wv.z + g.w * wv.w;
        #pragma unroll
        for (int off = 1; off < 32; off <<= 1) part += __shfl_xor(part, off, 64);
        if ((t & 31) == 0)
            sm[(size_t)b * R + r0 + row] =
                part + NEGV * (1.0f - mask[(size_t)b * R + r0 + row]);
        *(float4*)&tile[row][c4 * 4] = g;
    }
    __syncthreads();
    int d = t >> 1, rh = (t & 1) * 32;
    #pragma unroll
    for (int k = 0; k < 8; ++k) {
        bf4 o;
        #pragma unroll
        for (int i = 0; i < 4; ++i) o[i] = f2bf(tile[rh + k * 4 + i][d]);
        *(bf4*)&tr[((size_t)(b * DD + d)) * R + r0 + rh + k * 4] = o;
    }
}

#define SCP 1032   // k1 score row stride (bf16)
#define S2P 264    // k2 score row stride (bf16)
#define XTP 72     // [d][x] staged tile stride (16B-aligned rows, uniform bank spread)

// ---------------- k1: col softmax over c, AT[b][d][q] ----------------
// Phase A: direct-global A rows (1-deep reg prefetch, unrolled), B reg-resident.
// Phase C: cooperative LDS-staged B tiles with async-split prefetch (T14).
__global__ __launch_bounds__(256, 3) void k1_colsm(
        const short* __restrict__ xc_bf, const short* __restrict__ xcT_bf,
        const short* __restrict__ xqw_bf, const float* __restrict__ s0m,
        short* __restrict__ AT) {
    __shared__ __align__(16) short sc[16][SCP];   // 33.0 KB scores/weights [q][c]
    __shared__ __align__(16) short xct[DD][XTP];  // 18.4 KB staged xcT tile [d][c]
    __shared__ float invl[16];

    int bid = blockIdx.x;
    int qt = (bid >> 3) & 15;
    int b = ((bid >> 7) << 3) | (bid & 7);   // XCD-bijective: whole batch on one XCD
    int q0 = qt * 16;
    int t = threadIdx.x, w = t >> 6, l = t & 63;
    int quad = l >> 4, l16 = l & 15;

    // block-constant B-op: 16 xqw rows, fragment-resident
    bf8 bq[4];
    {
        const short* qp = &xqw_bf[(size_t)(b * QQ + q0 + l16) * DD + quad * 8];
        #pragma unroll
        for (int ks = 0; ks < 4; ++ks) bq[ks] = *(const bf8*)&qp[ks * 32];
    }

    // ---- phase A: S[c][q] for all 1024 c (M=c, N=q, K=d), barrier-free ----
    const short* abase = &xc_bf[(size_t)(b * CC + w * 16 + l16) * DD + quad * 8];
    const float* s0base = &s0m[b * CC + w * 16 + quad * 4];
    bf8 cur[4];
    #pragma unroll
    for (int ks = 0; ks < 4; ++ks) cur[ks] = *(const bf8*)&abase[ks * 32];
    #pragma unroll
    for (int ct = 0; ct < 16; ++ct) {
        bf8 nxt[4];
        if (ct < 15) {
            const short* ar = abase + (size_t)(ct + 1) * 64 * DD;
            #pragma unroll
            for (int ks = 0; ks < 4; ++ks) nxt[ks] = *(const bf8*)&ar[ks * 32];
        }
        f4v acc = {0.f, 0.f, 0.f, 0.f};
        #pragma unroll
        for (int ks = 0; ks < 4; ++ks)
            acc = __builtin_amdgcn_mfma_f32_16x16x32_bf16(cur[ks], bq[ks], acc, 0, 0, 0);
        f4v s0v = *(const f4v*)&s0base[ct * 64];
        bf4 ov;
        #pragma unroll
        for (int r = 0; r < 4; ++r) ov[r] = f2bf(acc[r] + s0v[r]);
        *(bf4*)&sc[l16][ct * 64 + w * 16 + quad * 4] = ov;  // col=q=l16, row=c
        #pragma unroll
        for (int ks = 0; ks < 4; ++ks) cur[ks] = nxt[ks];
    }

    // preload phase-C tile 0 into regs before the softmax (latency hidden there)
    int c8 = t & 7, dr = t >> 3;
    const short* tbase = &xcT_bf[(size_t)(b * DD + dr) * CC + c8 * 8];
    bf8 g[4];
    #pragma unroll
    for (int p = 0; p < 4; ++p)
        g[p] = *(const bf8*)&tbase[(size_t)(p * 32) * CC];

    __syncthreads();

    // ---- phase B: softmax over c per q ----
    {
        int q = t >> 4, k = t & 15;
        float m = -3.0e38f;
        #pragma unroll 8
        for (int i = 0; i < 64; ++i) m = fmaxf(m, bf2f(sc[q][k + 16 * i]));
        #pragma unroll
        for (int off = 1; off < 16; off <<= 1) m = fmaxf(m, __shfl_xor(m, off, 64));
        float sum = 0.f;
        #pragma unroll 8
        for (int i = 0; i < 64; ++i) {
            int idx = k + 16 * i;
            float e = __expf(bf2f(sc[q][idx]) - m);
            sc[q][idx] = f2bf(e);
            sum += e;
        }
        #pragma unroll
        for (int off = 1; off < 16; off <<= 1) sum += __shfl_xor(sum, off, 64);
        if (k == 0) invl[q] = 1.0f / sum;
    }
    __syncthreads();

    // ---- phase C: AT (M=q, N=d, K=c); A = sc LDS, B = staged xct tile ----
    f4v acc0 = {0.f, 0.f, 0.f, 0.f}, acc1 = {0.f, 0.f, 0.f, 0.f};
    for (int ct = 0; ct < 16; ++ct) {
        #pragma unroll
        for (int p = 0; p < 4; ++p)
            *(bf8*)&xct[dr + p * 32][c8 * 8] = g[p];
        if (ct < 15) {
            #pragma unroll
            for (int p = 0; p < 4; ++p)
                g[p] = *(const bf8*)&tbase[(size_t)(p * 32) * CC + (ct + 1) * 64];
        }
        __syncthreads();
        #pragma unroll
        for (int ks = 0; ks < 2; ++ks) {
            bf8 a = *(const bf8*)&sc[l16][ct * 64 + ks * 32 + quad * 8];
            bf8 b0 = *(const bf8*)&xct[w * 32 + l16][ks * 32 + quad * 8];
            acc0 = __builtin_amdgcn_mfma_f32_16x16x32_bf16(a, b0, acc0, 0, 0, 0);
            bf8 b1 = *(const bf8*)&xct[w * 32 + 16 + l16][ks * 32 + quad * 8];
            acc1 = __builtin_amdgcn_mfma_f32_16x16x32_bf16(a, b1, acc1, 0, 0, 0);
        }
        __syncthreads();
    }
    {
        bf4 o0, o1;
        #pragma unroll
        for (int r = 0; r < 4; ++r) {
            float il = invl[quad * 4 + r];
            o0[r] = f2bf(acc0[r] * il);
            o1[r] = f2bf(acc1[r] * il);
        }
        int d0 = w * 32 + l16;
        *(bf4*)&AT[(size_t)(b * DD + d0) * QQ + q0 + quad * 4] = o0;
        *(bf4*)&AT[(size_t)(b * DD + d0 + 16) * QQ + q0 + quad * 4] = o1;
    }
}

// ---------------- k2: row softmax over q, c2q / q2c, fused concat ----------------
__global__ __launch_bounds__(256, 4) void k2_rowsm(
        const float* __restrict__ xc, const short* __restrict__ xc_bf,
        const short* __restrict__ xqw_bf, const short* __restrict__ xqT_bf,
        const short* __restrict__ AT, const float* __restrict__ s1m,
        float* __restrict__ out) {
    __shared__ __align__(16) short sc2[32][S2P];  // 16.9 KB scores/weights [c][q]
    __shared__ __align__(16) short tT[DD][XTP];   // 18.4 KB staged xqT/AT tile [d][q]
    __shared__ float invl2[32];

    int bid = blockIdx.x;
    int cb = (bid >> 3) & 31;
    int b = ((bid >> 8) << 3) | (bid & 7);
    int c0g = cb * 32;
    int t = threadIdx.x, w = t >> 6, l = t & 63;
    int quad = l >> 4, l16 = l & 15;

    // block-constant B-op: 32 xc rows, fragment-resident
    bf8 bc0[4], bc1[4];
    {
        const short* p0 = &xc_bf[(size_t)(b * CC + c0g + l16) * DD + quad * 8];
        const short* p1 = p0 + 16 * DD;
        #pragma unroll
        for (int ks = 0; ks < 4; ++ks) {
            bc0[ks] = *(const bf8*)&p0[ks * 32];
            bc1[ks] = *(const bf8*)&p1[ks * 32];
        }
    }

    // ---- phase 1: S^T (M=q, N=c, K=d), barrier-free, 1-deep prefetch ----
    const short* abase = &xqw_bf[(size_t)(b * QQ + w * 16 + l16) * DD + quad * 8];
    const float* s1base = &s1m[b * QQ + w * 16 + quad * 4];
    bf8 cur[4];
    #pragma unroll
    for (int ks = 0; ks < 4; ++ks) cur[ks] = *(const bf8*)&abase[ks * 32];
    #pragma unroll
    for (int qt = 0; qt < 4; ++qt) {
        bf8 nxt[4];
        if (qt < 3) {
            const short* ar = abase + (size_t)(qt + 1) * 64 * DD;
            #pragma unroll
            for (int ks = 0; ks < 4; ++ks) nxt[ks] = *(const bf8*)&ar[ks * 32];
        }
        f4v acc0 = {0.f, 0.f, 0.f, 0.f}, acc1 = {0.f, 0.f, 0.f, 0.f};
        #pragma unroll
        for (int ks = 0; ks < 4; ++ks) {
            acc0 = __builtin_amdgcn_mfma_f32_16x16x32_bf16(cur[ks], bc0[ks], acc0, 0, 0, 0);
            acc1 = __builtin_amdgcn_mfma_f32_16x16x32_bf16(cur[ks], bc1[ks], acc1, 0, 0, 0);
        }
        int qbase = qt * 64 + w * 16 + quad * 4;
        f4v sv = *(const f4v*)&s1base[qt * 64];
        bf4 o0, o1;
        #pragma unroll
        for (int r = 0; r < 4; ++r) {
            o0[r] = f2bf(acc0[r] + sv[r]);
            o1[r] = f2bf(acc1[r] + sv[r]);
        }
        *(bf4*)&sc2[l16][qbase] = o0;        // col=c=l16, rows=q
        *(bf4*)&sc2[16 + l16][qbase] = o1;
        #pragma unroll
        for (int ks = 0; ks < 4; ++ks) cur[ks] = nxt[ks];
    }

    // preload phase-3 tile 0 (xqT, qt=0) before the softmax
    int q8 = t & 7, dr = t >> 3;
    const short* qtb = &xqT_bf[(size_t)(b * DD + dr) * QQ + q8 * 8];
    const short* atb = &AT[(size_t)(b * DD + dr) * QQ + q8 * 8];
    bf8 g[4];
    #pragma unroll
    for (int p = 0; p < 4; ++p)
        g[p] = *(const bf8*)&qtb[(size_t)(p * 32) * QQ];

    __syncthreads();

    // ---- phase 2: softmax over q per c ----
    {
        int c = t >> 3, k = t & 7;
        float m = -3.0e38f;
        #pragma unroll 8
        for (int i = 0; i < 32; ++i) m = fmaxf(m, bf2f(sc2[c][k + 8 * i]));
        #pragma unroll
        for (int off = 1; off < 8; off <<= 1) m = fmaxf(m, __shfl_xor(m, off, 64));
        float sum = 0.f;
        #pragma unroll 8
        for (int i = 0; i < 32; ++i) {
            int idx = k + 8 * i;
            float e = __expf(bf2f(sc2[c][idx]) - m);
            sc2[c][idx] = f2bf(e);
            sum += e;
        }
        #pragma unroll
        for (int off = 1; off < 8; off <<= 1) sum += __shfl_xor(sum, off, 64);
        if (k == 0) invl2[c] = 1.0f / sum;
    }
    __syncthreads();

    // ---- phase 3: c2q = W@xq, q2c = W@A (M=c, N=d, K=q), staged tiles ----
    int cb16 = (w & 1) * 16, dh = (w >> 1) * 64;
    f4v ac[4], aq[4];
    f4v zz = {0.f, 0.f, 0.f, 0.f};
    #pragma unroll
    for (int n = 0; n < 4; ++n) { ac[n] = zz; aq[n] = zz; }
    #pragma unroll
    for (int tl = 0; tl < 8; ++tl) {
        #pragma unroll
        for (int p = 0; p < 4; ++p)
            *(bf8*)&tT[dr + p * 32][q8 * 8] = g[p];
        if (tl < 7) {
            const short* s = (tl + 1 < 4) ? qtb : atb;
            int qq = ((tl + 1) & 3) * 64;
            #pragma unroll
            for (int p = 0; p < 4; ++p)
                g[p] = *(const bf8*)&s[(size_t)(p * 32) * QQ + qq];
        }
        __syncthreads();
        int qt = tl & 3;
        #pragma unroll
        for (int ks = 0; ks < 2; ++ks) {
            bf8 a = *(const bf8*)&sc2[cb16 + l16][qt * 64 + ks * 32 + quad * 8];
            #pragma unroll
            for (int n = 0; n < 4; ++n) {
                bf8 bb = *(const bf8*)&tT[dh + n * 16 + l16][ks * 32 + quad * 8];
                if (tl < 4) ac[n] = __builtin_amdgcn_mfma_f32_16x16x32_bf16(a, bb, ac[n], 0, 0, 0);
                else        aq[n] = __builtin_amdgcn_mfma_f32_16x16x32_bf16(a, bb, aq[n], 0, 0, 0);
            }
        }
        __syncthreads();
    }

    // ---- epilogue: concat([xc, c2q, xc*c2q, xc*q2c]) ----
    #pragma unroll
    for (int r = 0; r < 4; ++r) {
        int c = c0g + cb16 + quad * 4 + r;
        float il = invl2[cb16 + quad * 4 + r];
        const float* xrow = xc + (size_t)(b * CC + c) * DD;
        float* orow = out + (size_t)(b * CC + c) * (4 * DD);
        #pragma unroll
        for (int n = 0; n < 4; ++n) {
            int d = dh + n * 16 + l16;
            float xv = xrow[d];
            float c2v = ac[n][r] * il;
            float q2v = aq[n][r] * il;
            orow[d] = xv;
            orow[DD + d] = c2v;
            orow[2 * DD + d] = xv * c2v;
            orow[3 * DD + d] = xv * q2v;
        }
    }
}

extern "C" void kernel_launch(void* const* d_in, const int* in_sizes, int n_in,
                              void* d_out, int out_size, void* d_ws, size_t ws_size,
                              hipStream_t stream) {
    const float* x_cont = (const float*)d_in[0];
    const float* x_ques = (const float*)d_in[1];
    const float* c_mask = (const float*)d_in[2];
    const float* q_mask = (const float*)d_in[3];
    const float* W0     = (const float*)d_in[4];
    const float* W1     = (const float*)d_in[5];
    const float* W2     = (const float*)d_in[6];
    // bias cancels in both softmaxes.
    float* out = (float*)d_out;

    char* ws = (char*)d_ws;
    float* s0m    = (float*)ws;  ws += (size_t)BB * CC * 4;
    float* s1m    = (float*)ws;  ws += (size_t)BB * QQ * 4;
    short* xc_bf  = (short*)ws;  ws += (size_t)BB * CC * DD * 2;
    short* xqw_bf = (short*)ws;  ws += (size_t)BB * QQ * DD * 2;
    short* xcT_bf = (short*)ws;  ws += (size_t)BB * CC * DD * 2;
    short* xqT_bf = (short*)ws;  ws += (size_t)BB * QQ * DD * 2;
    short* AT     = (short*)ws;  // B*D*Q

    k0_fused<0><<<BB * (CC / 64), 256, 0, stream>>>(x_cont, W0, nullptr, c_mask,
                                                    s0m, xc_bf, xcT_bf, CC);
    k0_fused<1><<<BB * (QQ / 64), 256, 0, stream>>>(x_ques, W1, W2, q_mask,
                                                    s1m, xqw_bf, xqT_bf, QQ);
    k1_colsm<<<BB * 16, 256, 0, stream>>>(xc_bf, xcT_bf, xqw_bf, s0m, AT);
    k2_rowsm<<<BB * 32, 256, 0, stream>>>(x_cont, xc_bf, xqw_bf, xqT_bf, AT, s1m, out);
}